// Round 19
// baseline (97.564 us; speedup 1.0000x reference)
//
#include <hip/hip_runtime.h>
#include <hip/hip_bf16.h>

// Problem dims
#define BROWS 8192
#define IDIM 256
#define HDIM 512
#define KCAT 768    // I + H
#define G4 2048     // 4*H

typedef __bf16 bf16_t;
typedef bf16_t bf16x8 __attribute__((ext_vector_type(8)));
typedef float f32x4 __attribute__((ext_vector_type(4)));

__device__ __forceinline__ f32x4 mfma16(bf16x8 a, bf16x8 b, f32x4 c) {
    return __builtin_amdgcn_mfma_f32_16x16x32_bf16(a, b, c, 0, 0, 0);
}

__device__ __forceinline__ ushort f2bf(float f) {
    union { float f; unsigned u; } v; v.f = f;
    unsigned u = v.u;
    unsigned r = (u + 0x7fffu + ((u >> 16) & 1u)) >> 16;  // RNE, inputs finite
    return (ushort)r;
}

__device__ __forceinline__ float bf2f(ushort u) {
    union { unsigned u; float f; } v; v.u = (unsigned)u << 16; return v.f;
}

__device__ __forceinline__ float sigmoidf_(float x) {
    return 1.f / (1.f + __expf(-x));
}
__device__ __forceinline__ float tanhf_(float x) {
    return 1.f - 2.f / (__expf(2.f * x) + 1.f);   // safe at +/-inf
}

// async global -> LDS, 16 bytes per lane (lds dest: wave-uniform base + lane*16)
typedef __attribute__((address_space(1))) const unsigned gas_u32;
typedef __attribute__((address_space(3))) unsigned las_u32;
__device__ __forceinline__ void gld_lds16(const void* g, void* l) {
    __builtin_amdgcn_global_load_lds((gas_u32*)g, (las_u32*)l, 16, 0, 0);
}

// ---------------- prep: fp32 -> bf16 packing (float4 vectorized) ----------------
__global__ void __launch_bounds__(256) prep_kernel(
        const float* __restrict__ x, const float* __restrict__ h,
        const float* __restrict__ aw0, const float* __restrict__ aw1,
        const float* __restrict__ w_ih, const float* __restrict__ w_hh,
        const float* __restrict__ ow0,
        ushort* __restrict__ xh, ushort* __restrict__ baw0,
        ushort* __restrict__ baw1, ushort* __restrict__ wcat,
        ushort* __restrict__ bow0) {
    int idx = (blockIdx.x * 256 + threadIdx.x) * 4;
    const int N_XH = BROWS * KCAT;      // 6291456
    const int N_AW0 = IDIM * KCAT;      // 196608
    const int N_AW1 = IDIM * IDIM;      // 65536
    const int N_WCAT = G4 * KCAT;       // 1572864
    const int N_OW0 = HDIM * HDIM;      // 262144
    float4 v;
    ushort* dst;
    if (idx < N_XH) {
        int b = idx / KCAT, k = idx - b * KCAT;
        v = (k < IDIM) ? *(const float4*)&x[b * IDIM + k]
                       : *(const float4*)&h[b * HDIM + (k - IDIM)];
        dst = &xh[idx];
    } else if ((idx -= N_XH) < N_AW0) {
        v = *(const float4*)&aw0[idx]; dst = &baw0[idx];
    } else if ((idx -= N_AW0) < N_AW1) {
        v = *(const float4*)&aw1[idx]; dst = &baw1[idx];
    } else if ((idx -= N_AW1) < N_WCAT) {
        int o = idx / KCAT, k = idx - o * KCAT;
        v = (k < IDIM) ? *(const float4*)&w_ih[o * IDIM + k]
                       : *(const float4*)&w_hh[o * HDIM + (k - IDIM)];
        dst = &wcat[idx];
    } else if ((idx -= N_WCAT) < N_OW0) {
        v = *(const float4*)&ow0[idx]; dst = &bow0[idx];
    } else {
        return;
    }
    ushort4 o4 = { f2bf(v.x), f2bf(v.y), f2bf(v.z), f2bf(v.w) };
    *(ushort4*)dst = o4;
}

// ---------------- staged GEMM, 8-wave (R16-proven) ----------------
template<int RELU_BF16>
__global__ void __launch_bounds__(512, 4) staged_gemm(
        const ushort* __restrict__ A, const ushort* __restrict__ W,
        const float* __restrict__ bias, void* __restrict__ outp,
        int Kdim, int out_ld) {
    __shared__ ushort As[2][4096];   // 8 subtiles x 512
    __shared__ ushort Ws[2][2048];   // 4 subtiles x 512
    const int tid = threadIdx.x;
    const int lane = tid & 63, wave = tid >> 6;   // 8 waves
    const int wm = wave >> 1, wn = wave & 1;      // 4M x 2N
    const int r = lane & 15, g = lane >> 4;
    const int rb = blockIdx.x & 63, cb = blockIdx.x >> 6;
    const int row0 = rb * 128, col0 = cb * 64;
    const int rl = lane >> 2, chq = lane & 3;     // staging: row, chunk slot
    const int s_sw = (chq ^ ((rl >> 1) & 3)) * 8; // pre-swizzled source chunk
    const int rsw = (g ^ ((r >> 1) & 3)) * 8;     // read-side swizzle
    const bool doW = wave < 4;

    const ushort* aP = A + (size_t)(row0 + wave * 16 + rl) * Kdim + s_sw;
    const ushort* wP = W + (size_t)(col0 + (wave & 3) * 16 + rl) * Kdim + s_sw;

    f32x4 acc[2][2] = {};

    auto stage = [&](int buf, int t) {
        const int o = t * 32;
        gld_lds16(aP + o, &As[buf][wave * 512]);
        if (doW) gld_lds16(wP + o, &Ws[buf][(wave & 3) * 512]);
    };
    auto compute = [&](int buf) {
        bf16x8 af[2], wf[2];
#pragma unroll
        for (int m = 0; m < 2; m++)
            af[m] = *(const bf16x8*)&As[buf][(wm * 2 + m) * 512 + r * 32 + rsw];
#pragma unroll
        for (int n = 0; n < 2; n++)
            wf[n] = *(const bf16x8*)&Ws[buf][(wn * 2 + n) * 512 + r * 32 + rsw];
#pragma unroll
        for (int m = 0; m < 2; m++)
#pragma unroll
            for (int n = 0; n < 2; n++)
                acc[m][n] = mfma16(af[m], wf[n], acc[m][n]);
    };

    stage(0, 0);
    const int NT = Kdim >> 5;
    int cur = 0;
    for (int t = 0; t < NT; t++) {
        __builtin_amdgcn_s_barrier();            // A: slot cur^1 readers done
        if (t + 1 < NT) {
            stage(cur ^ 1, t + 1);
            if (doW) asm volatile("s_waitcnt vmcnt(2)" ::: "memory");
            else     asm volatile("s_waitcnt vmcnt(1)" ::: "memory");
        } else {
            asm volatile("s_waitcnt vmcnt(0)" ::: "memory");
        }
        __builtin_amdgcn_s_barrier();            // B: all waves' tile t in LDS
        compute(cur);
        cur ^= 1;
    }

#pragma unroll
    for (int n = 0; n < 2; n++) {
        int col = col0 + wn * 32 + n * 16 + r;
        float bv = bias[col];
#pragma unroll
        for (int m = 0; m < 2; m++) {
            int rbase = row0 + wm * 32 + m * 16 + g * 4;
#pragma unroll
            for (int reg = 0; reg < 4; reg++) {
                float v = acc[m][n][reg] + bv;
                if (RELU_BF16) {
                    v = v > 0.f ? v : 0.f;
                    ((ushort*)outp)[(size_t)(rbase + reg) * out_ld + col] = f2bf(v);
                } else {
                    ((float*)outp)[(size_t)(rbase + reg) * out_ld + col] = v;
                }
            }
        }
    }
}

// ---------------- fused logits GEMM + softmax + x*attn (R18-proven) ----------------
__global__ void __launch_bounds__(512) logits_softmax(
        const ushort* __restrict__ A, const ushort* __restrict__ W,
        const float* __restrict__ bias, const float* __restrict__ x,
        float* __restrict__ attn_out, ushort* __restrict__ xh) {
    __shared__ ushort As[2][1024];   // 2 subtiles x 512 (32 rows x 32 k)
    __shared__ ushort Ws[2][8192];   // 16 subtiles x 512 (256 rows x 32 k)
    __shared__ float lg[32][264];    // logits, padded
    const int tid = threadIdx.x;
    const int lane = tid & 63, wave = tid >> 6;   // 8 waves
    const int wm = wave >> 2, wn = wave & 3;      // 2M x 4N
    const int r = lane & 15, g = lane >> 4;
    const int row0 = blockIdx.x * 32;
    const int rl = lane >> 2, chq = lane & 3;
    const int s_sw = (chq ^ ((rl >> 1) & 3)) * 8;
    const int rsw = (g ^ ((r >> 1) & 3)) * 8;
    const bool doA = wave < 2;

    const ushort* aP  = A + (size_t)(row0 + wave * 16 + rl) * IDIM + s_sw;
    const ushort* wP0 = W + (size_t)(wave * 32 + rl) * IDIM + s_sw;
    const ushort* wP1 = W + (size_t)(wave * 32 + 16 + rl) * IDIM + s_sw;

    f32x4 acc[4] = {};

    auto stage = [&](int buf, int t) {
        const int o = t * 32;
        if (doA) gld_lds16(aP + o, &As[buf][wave * 512]);
        gld_lds16(wP0 + o, &Ws[buf][(2 * wave) * 512]);
        gld_lds16(wP1 + o, &Ws[buf][(2 * wave + 1) * 512]);
    };
    auto compute = [&](int buf) {
        bf16x8 af = *(const bf16x8*)&As[buf][wm * 512 + r * 32 + rsw];
        bf16x8 wf[4];
#pragma unroll
        for (int n = 0; n < 4; n++)
            wf[n] = *(const bf16x8*)&Ws[buf][(wn * 4 + n) * 512 + r * 32 + rsw];
#pragma unroll
        for (int n = 0; n < 4; n++)
            acc[n] = mfma16(af, wf[n], acc[n]);
    };

    stage(0, 0);
    const int NT = IDIM >> 5;   // 8
    int cur = 0;
    for (int t = 0; t < NT; t++) {
        __builtin_amdgcn_s_barrier();
        if (t + 1 < NT) {
            stage(cur ^ 1, t + 1);
            if (doA) asm volatile("s_waitcnt vmcnt(3)" ::: "memory");
            else     asm volatile("s_waitcnt vmcnt(2)" ::: "memory");
        } else {
            asm volatile("s_waitcnt vmcnt(0)" ::: "memory");
        }
        __builtin_amdgcn_s_barrier();
        compute(cur);
        cur ^= 1;
    }

#pragma unroll
    for (int n = 0; n < 4; n++) {
        int col = wn * 64 + n * 16 + r;
        float bv = bias[col];
#pragma unroll
        for (int reg = 0; reg < 4; reg++)
            lg[wm * 16 + g * 4 + reg][col] = acc[n][reg] + bv;
    }
    __syncthreads();

#pragma unroll
    for (int i = 0; i < 4; i++) {
        const int rr = wave * 4 + i;
        const int grow = row0 + rr;
        float v[4];
        float m = -1e30f;
#pragma unroll
        for (int j = 0; j < 4; j++) {
            v[j] = lg[rr][j * 64 + lane];
            m = fmaxf(m, v[j]);
        }
#pragma unroll
        for (int s = 32; s; s >>= 1) m = fmaxf(m, __shfl_xor(m, s, 64));
        float sum = 0.f;
#pragma unroll
        for (int j = 0; j < 4; j++) { v[j] = __expf(v[j] - m); sum += v[j]; }
#pragma unroll
        for (int s = 32; s; s >>= 1) sum += __shfl_xor(sum, s, 64);
        float inv = 1.f / sum;
#pragma unroll
        for (int j = 0; j < 4; j++) {
            int idx = j * 64 + lane;
            float a = v[j] * inv;
            attn_out[(size_t)grow * IDIM + idx] = a;
            xh[(size_t)grow * KCAT + idx] = f2bf(x[(size_t)grow * IDIM + idx] * a);
        }
    }
}

// ---------------- fused gates GEMM + LSTM epilogue (256x128, 2 blocks/CU) ----------------
// gates = [x_att|h] @ [w_ih|w_hh]^T : M=8192, j=512, 4 gates, K=768.
// Tile 256 rows x 128 cols (= 4 gates x 32 j). Staged bytes: A x16 + W x32
// = 302MB, but grid 32rb x 16cb = 512 blocks = 2 blocks/CU = 32 waves/CU
// -> bytes/wave 37KB vs R13's 49KB; model (0.35 B/cy/wave) predicts ~45us.
// 16 waves as 8M x 2N: wave tile 32x64 -> acc[2][4] = 32 VGPR (R12's same
// acc measured VGPR 36) -> fits the 64-VGPR cap of launch_bounds(1024,8)
// which forces 8 waves/SIMD = 2 blocks/CU. LDS 48KB: 2 bufs x (A 16KB + W 8KB).
// Gate-on-fragment preserved: cc = wn*64 + n*16 + r -> gate = (wn*4+n)&3 = n,
// j = j0 + wn*16 + r -> LSTM epilogue fully lane-local.
// Staging: wave w stages A-subtile w; waves 0-7 also stage W-subtile w.
// Two-barrier counted-vmcnt loop (vmcnt 2/1 by wave role); both-sides swizzle.
// XCD decode: xcd owns 4 rb x 16 cb (A-panel 1.5MB L2-resident).
__global__ void __launch_bounds__(1024, 8) gates_staged(
        const ushort* __restrict__ A, const ushort* __restrict__ W,
        const float* __restrict__ b_ih, const float* __restrict__ b_hh,
        const float* __restrict__ c_in,
        float* __restrict__ h_out, float* __restrict__ c_out,
        ushort* __restrict__ h_bf) {
    __shared__ ushort As[2 * 8192];   // 32KB: 2 bufs x 16 subtiles x 512
    __shared__ ushort Ws[2 * 4096];   // 16KB: 2 bufs x  8 subtiles x 512
    const int tid = threadIdx.x;
    const int lane = tid & 63, wave = tid >> 6;   // 16 waves
    const int wm = wave >> 1, wn = wave & 1;      // 8M x 2N
    const int r = lane & 15, g = lane >> 4;
    const int bid = blockIdx.x;                   // 512 blocks
    const int xcd = bid & 7, local = bid >> 3;    // local 0..63
    const int rb = xcd * 4 + (local & 3);         // 0..31
    const int cb = local >> 2;                    // 0..15
    const int row0 = rb * 256;
    const int j0 = cb * 32;
    const int rl = lane >> 2, chq = lane & 3;     // staging: row-in-subtile, chunk
    const int s_sw = (chq ^ ((rl >> 1) & 3)) * 8; // pre-swizzled source chunk
    const int rsw = (g ^ ((r >> 1) & 3)) * 8;     // read-side swizzle
    const bool doW = wave < 8;

    // W row for LDS col cc in [0,128): gate=(cc>>4)&3, j = j0+(cc&15)+((cc>>6)<<4)
    auto wrow = [&](int cc) {
        return ((cc >> 4) & 3) * HDIM + j0 + (cc & 15) + ((cc >> 6) << 4);
    };
    const ushort* aP = A + (size_t)(row0 + wave * 16 + rl) * KCAT + s_sw;
    const ushort* wP = W + (size_t)wrow(wave * 16 + rl) * KCAT + s_sw;  // valid when doW

    f32x4 acc[2][4] = {};

    auto stage = [&](int buf, int t) {
        const int o = t * 32;
        gld_lds16(aP + o, &As[buf * 8192 + wave * 512]);
        if (doW) gld_lds16(wP + o, &Ws[buf * 4096 + wave * 512]);
    };
    auto compute = [&](int buf) {
        bf16x8 af[2], wf[4];
#pragma unroll
        for (int m = 0; m < 2; m++)
            af[m] = *(const bf16x8*)&As[buf * 8192 + (wm * 2 + m) * 512 + r * 32 + rsw];
#pragma unroll
        for (int n = 0; n < 4; n++)
            wf[n] = *(const bf16x8*)&Ws[buf * 4096 + (wn * 4 + n) * 512 + r * 32 + rsw];
#pragma unroll
        for (int m = 0; m < 2; m++)
#pragma unroll
            for (int n = 0; n < 4; n++)
                acc[m][n] = mfma16(af[m], wf[n], acc[m][n]);
    };

    stage(0, 0);
    const int NT = KCAT >> 5;   // 24
    int cur = 0;
    for (int t = 0; t < NT; t++) {
        __builtin_amdgcn_s_barrier();            // A: slot cur^1 readers done
        if (t + 1 < NT) {
            stage(cur ^ 1, t + 1);
            if (doW) asm volatile("s_waitcnt vmcnt(2)" ::: "memory");
            else     asm volatile("s_waitcnt vmcnt(1)" ::: "memory");
        } else {
            asm volatile("s_waitcnt vmcnt(0)" ::: "memory");
        }
        __builtin_amdgcn_s_barrier();            // B: all waves' tile t in LDS
        compute(cur);
        cur ^= 1;
    }

    // LSTM epilogue: lane-local. j fixed per lane; gate = fragment index n.
    const int j = j0 + wn * 16 + r;
    float bb[4];
#pragma unroll
    for (int n = 0; n < 4; n++) bb[n] = b_ih[n * HDIM + j] + b_hh[n * HDIM + j];
#pragma unroll
    for (int m = 0; m < 2; m++) {
        int rbase = row0 + wm * 32 + m * 16 + g * 4;
#pragma unroll
        for (int reg = 0; reg < 4; reg++) {
            int row = rbase + reg;
            float ig = sigmoidf_(acc[m][0][reg] + bb[0]);
            float fg = sigmoidf_(acc[m][1][reg] + bb[1]);
            float gg = tanhf_(acc[m][2][reg] + bb[2]);
            float og = sigmoidf_(acc[m][3][reg] + bb[3]);
            float cn = fg * c_in[(size_t)row * HDIM + j] + ig * gg;
            float hn = og * tanhf_(cn);
            c_out[(size_t)row * HDIM + j] = cn;
            h_out[(size_t)row * HDIM + j] = hn;
            h_bf[(size_t)row * HDIM + j] = f2bf(hn);
        }
    }
}

// ---------------- head GEMV: out = sigmoid(hrelu . ow1 + ob1) ----------------
__global__ void __launch_bounds__(256) head_gemv(
        const ushort* __restrict__ Hrelu, const float* __restrict__ ow1,
        const float* __restrict__ ob1, float* __restrict__ outp) {
    const int wave = threadIdx.x >> 6, lane = threadIdx.x & 63;
    const int row = blockIdx.x * 4 + wave;
    typedef ushort u16x8 __attribute__((ext_vector_type(8)));
    u16x8 hv = *(const u16x8*)&Hrelu[(size_t)row * HDIM + lane * 8];
    float4 w0 = *(const float4*)&ow1[lane * 8];
    float4 w1 = *(const float4*)&ow1[lane * 8 + 4];
    float s = bf2f(hv[0]) * w0.x + bf2f(hv[1]) * w0.y + bf2f(hv[2]) * w0.z +
              bf2f(hv[3]) * w0.w + bf2f(hv[4]) * w1.x + bf2f(hv[5]) * w1.y +
              bf2f(hv[6]) * w1.z + bf2f(hv[7]) * w1.w;
#pragma unroll
    for (int sh = 32; sh; sh >>= 1) s += __shfl_xor(s, sh, 64);
    if (lane == 0) outp[row] = 1.f / (1.f + __expf(-(s + ob1[0])));
}

extern "C" void kernel_launch(void* const* d_in, const int* in_sizes, int n_in,
                              void* d_out, int out_size, void* d_ws, size_t ws_size,
                              hipStream_t stream) {
    const float* x    = (const float*)d_in[0];
    const float* h    = (const float*)d_in[1];
    const float* c    = (const float*)d_in[2];
    const float* aw0  = (const float*)d_in[3];
    const float* ab0  = (const float*)d_in[4];
    const float* aw1  = (const float*)d_in[5];
    const float* ab1  = (const float*)d_in[6];
    const float* w_ih = (const float*)d_in[7];
    const float* b_ih = (const float*)d_in[8];
    const float* w_hh = (const float*)d_in[9];
    const float* b_hh = (const float*)d_in[10];
    const float* ow0  = (const float*)d_in[11];
    const float* ob0  = (const float*)d_in[12];
    const float* ow1  = (const float*)d_in[13];
    const float* ob1  = (const float*)d_in[14];

    char* ws = (char*)d_ws;
    ushort* xh     = (ushort*)(ws + 0);           // 8192*768*2  = 12582912
    ushort* a0     = (ushort*)(ws + 12582912);    // 8192*256*2  = 4194304
    ushort* hrelu  = (ushort*)(ws + 16777216);    // 8192*512*2  = 8388608
    ushort* hbf    = (ushort*)(ws + 25165824);    // 8192*512*2  = 8388608
    ushort* baw0   = (ushort*)(ws + 33554432);    // 256*768*2   = 393216
    ushort* baw1   = (ushort*)(ws + 33947648);    // 256*256*2   = 131072
    ushort* wcat   = (ushort*)(ws + 34078720);    // 2048*768*2  = 3145728
    ushort* bow0   = (ushort*)(ws + 37224448);    // 512*512*2   = 524288

    float* outv    = (float*)d_out;               // [8192]
    float* h_out   = outv + 8192;                 // [8192,512]
    float* c_out   = outv + 4202496;              // [8192,512]
    float* attn_o  = outv + 8396800;              // [8192,256]

    prep_kernel<<<8192, 256, 0, stream>>>(x, h, aw0, aw1, w_ih, w_hh, ow0,
                                          xh, baw0, baw1, wcat, bow0);
    // a0 = relu(xh @ aw0^T + ab0)         M=8192 N=256 K=768 -> 64x4 = 256 blocks (8-wave)
    staged_gemm<1><<<256, 512, 0, stream>>>(xh, baw0, ab0, a0, KCAT, IDIM);
    // logits + softmax + x*attn fused     M=8192 N=256 K=256 -> 256 blocks (8-wave)
    logits_softmax<<<256, 512, 0, stream>>>(a0, baw1, ab1, x, attn_o, xh);
    // fused LSTM gates                    M=8192 N=2048 K=768 -> 32x16 = 512 blocks (16-wave, 2/CU)
    gates_staged<<<512, 1024, 0, stream>>>(xh, wcat, b_ih, b_hh, c,
                                           h_out, c_out, hbf);
    // hrelu = relu(h_new @ ow0^T + ob0)   M=8192 N=512 K=512 -> 64x8 = 512 blocks (8-wave, 2/CU)
    staged_gemm<1><<<512, 512, 0, stream>>>(hbf, bow0, ob0, hrelu, HDIM, HDIM);
    head_gemv<<<2048, 256, 0, stream>>>(hrelu, ow1, ob1, outv);
}

// Round 20
// 85.845 us; speedup vs baseline: 1.1365x; 1.1365x over previous
//
#include <hip/hip_runtime.h>
#include <hip/hip_bf16.h>

// Problem dims
#define BROWS 8192
#define IDIM 256
#define HDIM 512
#define KCAT 768    // I + H
#define G4 2048    // 4*H

typedef __bf16 bf16_t;
typedef bf16_t bf16x8 __attribute__((ext_vector_type(8)));
typedef float f32x4 __attribute__((ext_vector_type(4)));

__device__ __forceinline__ f32x4 mfma16(bf16x8 a, bf16x8 b, f32x4 c) {
    return __builtin_amdgcn_mfma_f32_16x16x32_bf16(a, b, c, 0, 0, 0);
}

__device__ __forceinline__ ushort f2bf(float f) {
    union { float f; unsigned u; } v; v.f = f;
    unsigned u = v.u;
    unsigned r = (u + 0x7fffu + ((u >> 16) & 1u)) >> 16;  // RNE, inputs finite
    return (ushort)r;
}

__device__ __forceinline__ float bf2f(ushort u) {
    union { unsigned u; float f; } v; v.u = (unsigned)u << 16; return v.f;
}

__device__ __forceinline__ float sigmoidf_(float x) {
    return 1.f / (1.f + __expf(-x));
}
__device__ __forceinline__ float tanhf_(float x) {
    return 1.f - 2.f / (__expf(2.f * x) + 1.f);   // safe at +/-inf
}

// async global -> LDS, 16 bytes per lane (lds dest: wave-uniform base + lane*16)
typedef __attribute__((address_space(1))) const unsigned gas_u32;
typedef __attribute__((address_space(3))) unsigned las_u32;
__device__ __forceinline__ void gld_lds16(const void* g, void* l) {
    __builtin_amdgcn_global_load_lds((gas_u32*)g, (las_u32*)l, 16, 0, 0);
}

// ---------------- prep: fp32 -> bf16 packing (float4 vectorized) ----------------
__global__ void __launch_bounds__(256) prep_kernel(
        const float* __restrict__ x, const float* __restrict__ h,
        const float* __restrict__ aw0, const float* __restrict__ aw1,
        const float* __restrict__ w_ih, const float* __restrict__ w_hh,
        const float* __restrict__ ow0,
        ushort* __restrict__ xh, ushort* __restrict__ baw0,
        ushort* __restrict__ baw1, ushort* __restrict__ wcat,
        ushort* __restrict__ bow0) {
    int idx = (blockIdx.x * 256 + threadIdx.x) * 4;
    const int N_XH = BROWS * KCAT;      // 6291456
    const int N_AW0 = IDIM * KCAT;      // 196608
    const int N_AW1 = IDIM * IDIM;      // 65536
    const int N_WCAT = G4 * KCAT;       // 1572864
    const int N_OW0 = HDIM * HDIM;      // 262144
    float4 v;
    ushort* dst;
    if (idx < N_XH) {
        int b = idx / KCAT, k = idx - b * KCAT;
        v = (k < IDIM) ? *(const float4*)&x[b * IDIM + k]
                       : *(const float4*)&h[b * HDIM + (k - IDIM)];
        dst = &xh[idx];
    } else if ((idx -= N_XH) < N_AW0) {
        v = *(const float4*)&aw0[idx]; dst = &baw0[idx];
    } else if ((idx -= N_AW0) < N_AW1) {
        v = *(const float4*)&aw1[idx]; dst = &baw1[idx];
    } else if ((idx -= N_AW1) < N_WCAT) {
        int o = idx / KCAT, k = idx - o * KCAT;
        v = (k < IDIM) ? *(const float4*)&w_ih[o * IDIM + k]
                       : *(const float4*)&w_hh[o * HDIM + (k - IDIM)];
        dst = &wcat[idx];
    } else if ((idx -= N_WCAT) < N_OW0) {
        v = *(const float4*)&ow0[idx]; dst = &bow0[idx];
    } else {
        return;
    }
    ushort4 o4 = { f2bf(v.x), f2bf(v.y), f2bf(v.z), f2bf(v.w) };
    *(ushort4*)dst = o4;
}

// ---------------- staged GEMM, 8-wave (R16-proven) ----------------
// Tile 128 x 64, BK=32. 8 waves (512 thr, 4M x 2N), wave tile 32x32.
// Two-barrier counted-vmcnt loop; both-sides chunk-XOR swizzle.
template<int RELU_BF16>
__global__ void __launch_bounds__(512, 4) staged_gemm(
        const ushort* __restrict__ A, const ushort* __restrict__ W,
        const float* __restrict__ bias, void* __restrict__ outp,
        int Kdim, int out_ld) {
    __shared__ ushort As[2][4096];   // 8 subtiles x 512
    __shared__ ushort Ws[2][2048];   // 4 subtiles x 512
    const int tid = threadIdx.x;
    const int lane = tid & 63, wave = tid >> 6;   // 8 waves
    const int wm = wave >> 1, wn = wave & 1;      // 4M x 2N
    const int r = lane & 15, g = lane >> 4;
    const int rb = blockIdx.x & 63, cb = blockIdx.x >> 6;
    const int row0 = rb * 128, col0 = cb * 64;
    const int rl = lane >> 2, chq = lane & 3;     // staging: row, chunk slot
    const int s_sw = (chq ^ ((rl >> 1) & 3)) * 8; // pre-swizzled source chunk
    const int rsw = (g ^ ((r >> 1) & 3)) * 8;     // read-side swizzle
    const bool doW = wave < 4;

    const ushort* aP = A + (size_t)(row0 + wave * 16 + rl) * Kdim + s_sw;
    const ushort* wP = W + (size_t)(col0 + (wave & 3) * 16 + rl) * Kdim + s_sw;

    f32x4 acc[2][2] = {};

    auto stage = [&](int buf, int t) {
        const int o = t * 32;
        gld_lds16(aP + o, &As[buf][wave * 512]);
        if (doW) gld_lds16(wP + o, &Ws[buf][(wave & 3) * 512]);
    };
    auto compute = [&](int buf) {
        bf16x8 af[2], wf[2];
#pragma unroll
        for (int m = 0; m < 2; m++)
            af[m] = *(const bf16x8*)&As[buf][(wm * 2 + m) * 512 + r * 32 + rsw];
#pragma unroll
        for (int n = 0; n < 2; n++)
            wf[n] = *(const bf16x8*)&Ws[buf][(wn * 2 + n) * 512 + r * 32 + rsw];
#pragma unroll
        for (int m = 0; m < 2; m++)
#pragma unroll
            for (int n = 0; n < 2; n++)
                acc[m][n] = mfma16(af[m], wf[n], acc[m][n]);
    };

    stage(0, 0);
    const int NT = Kdim >> 5;
    int cur = 0;
    for (int t = 0; t < NT; t++) {
        __builtin_amdgcn_s_barrier();            // A: slot cur^1 readers done
        if (t + 1 < NT) {
            stage(cur ^ 1, t + 1);
            if (doW) asm volatile("s_waitcnt vmcnt(2)" ::: "memory");
            else     asm volatile("s_waitcnt vmcnt(1)" ::: "memory");
        } else {
            asm volatile("s_waitcnt vmcnt(0)" ::: "memory");
        }
        __builtin_amdgcn_s_barrier();            // B: all waves' tile t in LDS
        compute(cur);
        cur ^= 1;
    }

#pragma unroll
    for (int n = 0; n < 2; n++) {
        int col = col0 + wn * 32 + n * 16 + r;
        float bv = bias[col];
#pragma unroll
        for (int m = 0; m < 2; m++) {
            int rbase = row0 + wm * 32 + m * 16 + g * 4;
#pragma unroll
            for (int reg = 0; reg < 4; reg++) {
                float v = acc[m][n][reg] + bv;
                if (RELU_BF16) {
                    v = v > 0.f ? v : 0.f;
                    ((ushort*)outp)[(size_t)(rbase + reg) * out_ld + col] = f2bf(v);
                } else {
                    ((float*)outp)[(size_t)(rbase + reg) * out_ld + col] = v;
                }
            }
        }
    }
}

// ---------------- fused logits GEMM + softmax + x*attn (R18-proven) ----------------
// logits = a0 @ aw1^T + ab1 (M=8192, N=256, K=256), then rowwise softmax,
// then attn_out = softmax, xh[:, :256] = bf16(x * softmax).
// Block = 32 rows x ALL 256 cols; grid 256 = 1 block/CU. 8 waves (2M x 4N).
__global__ void __launch_bounds__(512) logits_softmax(
        const ushort* __restrict__ A, const ushort* __restrict__ W,
        const float* __restrict__ bias, const float* __restrict__ x,
        float* __restrict__ attn_out, ushort* __restrict__ xh) {
    __shared__ ushort As[2][1024];   // 2 subtiles x 512 (32 rows x 32 k)
    __shared__ ushort Ws[2][8192];   // 16 subtiles x 512 (256 rows x 32 k)
    __shared__ float lg[32][264];    // logits, padded
    const int tid = threadIdx.x;
    const int lane = tid & 63, wave = tid >> 6;   // 8 waves
    const int wm = wave >> 2, wn = wave & 3;      // 2M x 4N
    const int r = lane & 15, g = lane >> 4;
    const int row0 = blockIdx.x * 32;
    const int rl = lane >> 2, chq = lane & 3;
    const int s_sw = (chq ^ ((rl >> 1) & 3)) * 8;
    const int rsw = (g ^ ((r >> 1) & 3)) * 8;
    const bool doA = wave < 2;

    const ushort* aP  = A + (size_t)(row0 + wave * 16 + rl) * IDIM + s_sw;
    const ushort* wP0 = W + (size_t)(wave * 32 + rl) * IDIM + s_sw;
    const ushort* wP1 = W + (size_t)(wave * 32 + 16 + rl) * IDIM + s_sw;

    f32x4 acc[4] = {};

    auto stage = [&](int buf, int t) {
        const int o = t * 32;
        if (doA) gld_lds16(aP + o, &As[buf][wave * 512]);
        gld_lds16(wP0 + o, &Ws[buf][(2 * wave) * 512]);
        gld_lds16(wP1 + o, &Ws[buf][(2 * wave + 1) * 512]);
    };
    auto compute = [&](int buf) {
        bf16x8 af = *(const bf16x8*)&As[buf][wm * 512 + r * 32 + rsw];
        bf16x8 wf[4];
#pragma unroll
        for (int n = 0; n < 4; n++)
            wf[n] = *(const bf16x8*)&Ws[buf][(wn * 4 + n) * 512 + r * 32 + rsw];
#pragma unroll
        for (int n = 0; n < 4; n++)
            acc[n] = mfma16(af, wf[n], acc[n]);
    };

    stage(0, 0);
    const int NT = IDIM >> 5;   // 8
    int cur = 0;
    for (int t = 0; t < NT; t++) {
        __builtin_amdgcn_s_barrier();
        if (t + 1 < NT) {
            stage(cur ^ 1, t + 1);
            if (doA) asm volatile("s_waitcnt vmcnt(3)" ::: "memory");
            else     asm volatile("s_waitcnt vmcnt(2)" ::: "memory");
        } else {
            asm volatile("s_waitcnt vmcnt(0)" ::: "memory");
        }
        __builtin_amdgcn_s_barrier();
        compute(cur);
        cur ^= 1;
    }

    // write logits (+bias) to LDS
#pragma unroll
    for (int n = 0; n < 4; n++) {
        int col = wn * 64 + n * 16 + r;
        float bv = bias[col];
#pragma unroll
        for (int reg = 0; reg < 4; reg++)
            lg[wm * 16 + g * 4 + reg][col] = acc[n][reg] + bv;
    }
    __syncthreads();

    // per-wave softmax over 4 rows (identical math to the verified attn_softmax)
#pragma unroll
    for (int i = 0; i < 4; i++) {
        const int rr = wave * 4 + i;
        const int grow = row0 + rr;
        float v[4];
        float m = -1e30f;
#pragma unroll
        for (int j = 0; j < 4; j++) {
            v[j] = lg[rr][j * 64 + lane];
            m = fmaxf(m, v[j]);
        }
#pragma unroll
        for (int s = 32; s; s >>= 1) m = fmaxf(m, __shfl_xor(m, s, 64));
        float sum = 0.f;
#pragma unroll
        for (int j = 0; j < 4; j++) { v[j] = __expf(v[j] - m); sum += v[j]; }
#pragma unroll
        for (int s = 32; s; s >>= 1) sum += __shfl_xor(sum, s, 64);
        float inv = 1.f / sum;
#pragma unroll
        for (int j = 0; j < 4; j++) {
            int idx = j * 64 + lane;
            float a = v[j] * inv;
            attn_out[(size_t)grow * IDIM + idx] = a;
            xh[(size_t)grow * KCAT + idx] = f2bf(x[(size_t)grow * IDIM + idx] * a);
        }
    }
}

// ---------------- fused gates GEMM + LSTM epilogue (R13-exact, plateau config) ----------------
// gates = [x_att|h] @ [w_ih|w_hh]^T : M=8192, j=512, 4 gates, K=768.
// 256x256 tile (201MB staged, min-bytes + L2-resident re-reads), BK=32,
// 16 waves (1024 thr, 4M x 4N), wave 64x64 (acc[4][4]=64 VGPR).
// Grid 32x8 = 256 = 1 block/CU, zero tail. LDS 64KB 2-slot; both-sides
// chunk-XOR swizzle; counted-vmcnt two-barrier loop. Measured plateau:
// 54us; BK=64 (R14), prefetch-depth (R15), 256x128/2-blk (R19) all null
// or worse -- R19 showed bigger tiles' extra A re-reads spill L2 (FETCH
// 26.8 -> 41.8MB), so this is the corrected-model optimum.
__global__ void __launch_bounds__(1024, 4) gates_staged(
        const ushort* __restrict__ A, const ushort* __restrict__ W,
        const float* __restrict__ b_ih, const float* __restrict__ b_hh,
        const float* __restrict__ c_in,
        float* __restrict__ h_out, float* __restrict__ c_out,
        ushort* __restrict__ h_bf) {
    __shared__ ushort As[2 * 8192];   // 32KB: 2 bufs x 16 subtiles x 512
    __shared__ ushort Ws[2 * 8192];   // 32KB
    const int tid = threadIdx.x;
    const int lane = tid & 63, wave = tid >> 6;   // 16 waves
    const int wm = wave >> 2, wn = wave & 3;      // 4M x 4N
    const int r = lane & 15, g = lane >> 4;
    const int bid = blockIdx.x;                   // 256 blocks
    const int xcd = bid & 7, local = bid >> 3;
    const int rb = xcd * 4 + (local & 3);         // 0..31
    const int cb = local >> 2;                    // 0..7
    const int row0 = rb * 256;
    const int j0 = cb * 64;
    const int rl = lane >> 2, chq = lane & 3;     // staging: row-in-subtile, chunk
    const int s_sw = (chq ^ ((rl >> 1) & 3)) * 8; // pre-swizzled source chunk
    const int rsw = (g ^ ((r >> 1) & 3)) * 8;     // read-side swizzle

    // W row for LDS col cc: gate=(cc>>4)&3, j = j0 + (cc&15) + ((cc>>6)<<4)
    auto wrow = [&](int cc) {
        return ((cc >> 4) & 3) * HDIM + j0 + (cc & 15) + ((cc >> 6) << 4);
    };
    const ushort* aP = A + (size_t)(row0 + wave * 16 + rl) * KCAT + s_sw;
    const ushort* wP = W + (size_t)wrow(wave * 16 + rl) * KCAT + s_sw;

    f32x4 acc[4][4] = {};

    auto stage = [&](int buf, int t) {
        const int o = t * 32;
        gld_lds16(aP + o, &As[buf * 8192 + wave * 512]);
        gld_lds16(wP + o, &Ws[buf * 8192 + wave * 512]);
    };
    auto compute = [&](int buf) {
        bf16x8 af[4], wf[4];
#pragma unroll
        for (int m = 0; m < 4; m++)
            af[m] = *(const bf16x8*)&As[buf * 8192 + (wm * 4 + m) * 512 + r * 32 + rsw];
#pragma unroll
        for (int n = 0; n < 4; n++)
            wf[n] = *(const bf16x8*)&Ws[buf * 8192 + (wn * 4 + n) * 512 + r * 32 + rsw];
#pragma unroll
        for (int m = 0; m < 4; m++)
#pragma unroll
            for (int n = 0; n < 4; n++)
                acc[m][n] = mfma16(af[m], wf[n], acc[m][n]);
    };

    stage(0, 0);
    const int NT = KCAT >> 5;   // 24
    int cur = 0;
    for (int t = 0; t < NT; t++) {
        __builtin_amdgcn_s_barrier();            // A: slot cur^1 readers done
        if (t + 1 < NT) {
            stage(cur ^ 1, t + 1);
            asm volatile("s_waitcnt vmcnt(2)" ::: "memory");  // own tile t landed
        } else {
            asm volatile("s_waitcnt vmcnt(0)" ::: "memory");
        }
        __builtin_amdgcn_s_barrier();            // B: all waves' tile t in LDS
        compute(cur);
        cur ^= 1;
    }

    // LSTM epilogue: lane-local. j fixed per lane; gate = fragment index n.
    const int j = j0 + wn * 16 + r;
    float bb[4];
#pragma unroll
    for (int n = 0; n < 4; n++) bb[n] = b_ih[n * HDIM + j] + b_hh[n * HDIM + j];
#pragma unroll
    for (int m = 0; m < 4; m++) {
        int rbase = row0 + wm * 64 + m * 16 + g * 4;
#pragma unroll
        for (int reg = 0; reg < 4; reg++) {
            int row = rbase + reg;
            float ig = sigmoidf_(acc[m][0][reg] + bb[0]);
            float fg = sigmoidf_(acc[m][1][reg] + bb[1]);
            float gg = tanhf_(acc[m][2][reg] + bb[2]);
            float og = sigmoidf_(acc[m][3][reg] + bb[3]);
            float cn = fg * c_in[(size_t)row * HDIM + j] + ig * gg;
            float hn = og * tanhf_(cn);
            c_out[(size_t)row * HDIM + j] = cn;
            h_out[(size_t)row * HDIM + j] = hn;
            h_bf[(size_t)row * HDIM + j] = f2bf(hn);
        }
    }
}

// ---------------- head GEMV: out = sigmoid(hrelu . ow1 + ob1) ----------------
__global__ void __launch_bounds__(256) head_gemv(
        const ushort* __restrict__ Hrelu, const float* __restrict__ ow1,
        const float* __restrict__ ob1, float* __restrict__ outp) {
    const int wave = threadIdx.x >> 6, lane = threadIdx.x & 63;
    const int row = blockIdx.x * 4 + wave;
    typedef ushort u16x8 __attribute__((ext_vector_type(8)));
    u16x8 hv = *(const u16x8*)&Hrelu[(size_t)row * HDIM + lane * 8];
    float4 w0 = *(const float4*)&ow1[lane * 8];
    float4 w1 = *(const float4*)&ow1[lane * 8 + 4];
    float s = bf2f(hv[0]) * w0.x + bf2f(hv[1]) * w0.y + bf2f(hv[2]) * w0.z +
              bf2f(hv[3]) * w0.w + bf2f(hv[4]) * w1.x + bf2f(hv[5]) * w1.y +
              bf2f(hv[6]) * w1.z + bf2f(hv[7]) * w1.w;
#pragma unroll
    for (int sh = 32; sh; sh >>= 1) s += __shfl_xor(s, sh, 64);
    if (lane == 0) outp[row] = 1.f / (1.f + __expf(-(s + ob1[0])));
}

extern "C" void kernel_launch(void* const* d_in, const int* in_sizes, int n_in,
                              void* d_out, int out_size, void* d_ws, size_t ws_size,
                              hipStream_t stream) {
    const float* x    = (const float*)d_in[0];
    const float* h    = (const float*)d_in[1];
    const float* c    = (const float*)d_in[2];
    const float* aw0  = (const float*)d_in[3];
    const float* ab0  = (const float*)d_in[4];
    const float* aw1  = (const float*)d_in[5];
    const float* ab1  = (const float*)d_in[6];
    const float* w_ih = (const float*)d_in[7];
    const float* b_ih = (const float*)d_in[8];
    const float* w_hh = (const float*)d_in[9];
    const float* b_hh = (const float*)d_in[10];
    const float* ow0  = (const float*)d_in[11];
    const float* ob0  = (const float*)d_in[12];
    const float* ow1  = (const float*)d_in[13];
    const float* ob1  = (const float*)d_in[14];

    char* ws = (char*)d_ws;
    ushort* xh     = (ushort*)(ws + 0);           // 8192*768*2  = 12582912
    ushort* a0     = (ushort*)(ws + 12582912);    // 8192*256*2  = 4194304
    ushort* hrelu  = (ushort*)(ws + 16777216);    // 8192*512*2  = 8388608
    ushort* hbf    = (ushort*)(ws + 25165824);    // 8192*512*2  = 8388608
    ushort* baw0   = (ushort*)(ws + 33554432);    // 256*768*2   = 393216
    ushort* baw1   = (ushort*)(ws + 33947648);    // 256*256*2   = 131072
    ushort* wcat   = (ushort*)(ws + 34078720);    // 2048*768*2  = 3145728
    ushort* bow0   = (ushort*)(ws + 37224448);    // 512*512*2   = 524288

    float* outv    = (float*)d_out;               // [8192]
    float* h_out   = outv + 8192;                 // [8192,512]
    float* c_out   = outv + 4202496;              // [8192,512]
    float* attn_o  = outv + 8396800;              // [8192,256]

    prep_kernel<<<8192, 256, 0, stream>>>(x, h, aw0, aw1, w_ih, w_hh, ow0,
                                          xh, baw0, baw1, wcat, bow0);
    // a0 = relu(xh @ aw0^T + ab0)         M=8192 N=256 K=768 -> 64x4 = 256 blocks (8-wave)
    staged_gemm<1><<<256, 512, 0, stream>>>(xh, baw0, ab0, a0, KCAT, IDIM);
    // logits + softmax + x*attn fused     M=8192 N=256 K=256 -> 256 blocks (8-wave)
    logits_softmax<<<256, 512, 0, stream>>>(a0, baw1, ab1, x, attn_o, xh);
    // fused LSTM gates                    M=8192 N=2048 K=768 -> 32x8 = 256 blocks (16-wave)
    gates_staged<<<256, 1024, 0, stream>>>(xh, wcat, b_ih, b_hh, c,
                                           h_out, c_out, hbf);
    // hrelu = relu(h_new @ ow0^T + ob0)   M=8192 N=512 K=512 -> 64x8 = 512 blocks (8-wave, 2/CU)
    staged_gemm<1><<<512, 512, 0, stream>>>(hbf, bow0, ob0, hrelu, HDIM, HDIM);
    head_gemv<<<2048, 256, 0, stream>>>(hrelu, ow1, ob1, outv);
}